// Round 1
// 3241.667 us; speedup vs baseline: 1.5565x; 1.5565x over previous
//
#include <hip/hip_runtime.h>
#include <hip/hip_bf16.h>

// ---------------- problem shape ----------------
#define TT 64
#define BB 256
#define DD 1024
#define HH 1024
#define G4 4096    // 4*H
#define CHT 16     // xg chunk length (timesteps); 4 chunks cover T=64

typedef __bf16 bf16x8 __attribute__((ext_vector_type(8)));
typedef float  f32x4  __attribute__((ext_vector_type(4)));

// ---------------- static device scratch (no d_ws, no API calls) ----------------
__device__ unsigned short g_seq [(size_t)TT * BB * 1024];  // x (bf16) -> layer-1 h seq   32 MB
__device__ unsigned short g_Wih [(size_t)2 * G4 * 1024];   // 16 MB
__device__ unsigned short g_Whh [(size_t)2 * G4 * 1024];   // 16 MB
__device__ unsigned short g_Wfh [(size_t)2 * G4 * 1024];   // 16 MB
__device__ unsigned short g_feat[(size_t)BB * 1024];       // 0.5 MB
__device__ unsigned short g_xg  [(size_t)CHT * BB * G4];   // bf16 gates chunk            32 MB
__device__ unsigned short g_h   [2][(size_t)BB * HH];      // h state ping-pong (bf16)     1 MB
__device__ float          g_featb[(size_t)BB * G4];        // f32 feat@Wfh^T + b           4 MB
__device__ float          g_c   [(size_t)BB * HH];         // f32 cell state               1 MB

__device__ __forceinline__ bf16x8 ld8(const __hip_bfloat16* p) {
    return *reinterpret_cast<const bf16x8*>(p);
}
__device__ __forceinline__ __hip_bfloat16* BP(unsigned short* p) {
    return reinterpret_cast<__hip_bfloat16*>(p);
}
__device__ __forceinline__ const __hip_bfloat16* BPc(const unsigned short* p) {
    return reinterpret_cast<const __hip_bfloat16*>(p);
}

// direct global->LDS async copy, 16B per lane (guide m97: width=16 is the big lever)
typedef unsigned int u32_g __attribute__((address_space(1)));
typedef unsigned int u32_l __attribute__((address_space(3)));
__device__ __forceinline__ void gload16(const void* g, void* l) {
    __builtin_amdgcn_global_load_lds((const u32_g*)g, (u32_l*)l, 16, 0, 0);
}

// =============================================================
// f32 -> bf16 conversion into a selected device-global buffer.
// which: 0=g_seq 1=g_Wih 2=g_Whh 3=g_Wfh 4=g_feat. 4 elems/thread.
// =============================================================
__global__ __launch_bounds__(256) void cvt_bf16(int which,
                                                const float* __restrict__ s,
                                                size_t n)
{
    size_t i = ((size_t)blockIdx.x * 256 + threadIdx.x) * 4;
    if (i >= n) return;
    unsigned short* d = (which == 0) ? g_seq
                      : (which == 1) ? g_Wih
                      : (which == 2) ? g_Whh
                      : (which == 3) ? g_Wfh : g_feat;
    float4 v = *reinterpret_cast<const float4*>(s + i);
    __hip_bfloat16* db = BP(d) + i;
    db[0] = __float2bfloat16(v.x);
    db[1] = __float2bfloat16(v.y);
    db[2] = __float2bfloat16(v.z);
    db[3] = __float2bfloat16(v.w);
}

// =============================================================
// Small-M featb GEMM (unchanged, verified): C[256,4096] = feat @ Wfh^T + b (f32)
// =============================================================
template<bool FEATB>
__global__ __launch_bounds__(256) void gemm_k(size_t seq_off, size_t w_off,
                                              const float* __restrict__ bias)
{
    const int tid  = threadIdx.x;
    const int lane = tid & 63, wid = tid >> 6;
    const int row  = lane & 15, quad = lane >> 4;
    const int m_base = blockIdx.y * 128 + (wid >> 1) * 64;
    const int n_base = blockIdx.x * 64  + (wid & 1) * 32;

    const __hip_bfloat16* A = FEATB ? BPc(g_feat) : BPc(g_seq) + seq_off;
    const __hip_bfloat16* W = (FEATB ? BPc(g_Wfh) : BPc(g_Wih)) + w_off;

    f32x4 acc[4][2] = {};
    const __hip_bfloat16* Ap = A + (size_t)(m_base + row) * 1024 + quad * 8;
    const __hip_bfloat16* Wp = W + (size_t)(n_base + row) * 1024 + quad * 8;

    for (int k0 = 0; k0 < 1024; k0 += 32) {
        bf16x8 a[4], b[2];
#pragma unroll
        for (int i = 0; i < 4; ++i) a[i] = ld8(Ap + (size_t)(16 * i) * 1024 + k0);
#pragma unroll
        for (int j = 0; j < 2; ++j) b[j] = ld8(Wp + (size_t)(16 * j) * 1024 + k0);
#pragma unroll
        for (int i = 0; i < 4; ++i)
#pragma unroll
            for (int j = 0; j < 2; ++j)
                acc[i][j] = __builtin_amdgcn_mfma_f32_16x16x32_bf16(a[i], b[j], acc[i][j], 0, 0, 0);
    }

#pragma unroll
    for (int i = 0; i < 4; ++i) {
#pragma unroll
        for (int j = 0; j < 2; ++j) {
            const int n = n_base + 16 * j + row;
#pragma unroll
            for (int r = 0; r < 4; ++r) {
                const int m = m_base + 16 * i + quad * 4 + r;
                if (FEATB) {
                    g_featb[(size_t)m * G4 + n] = acc[i][j][r] + bias[n];
                } else {
                    float v = acc[i][j][r] + g_featb[(size_t)(m & 255) * G4 + n];
                    BP(g_xg)[(size_t)m * G4 + n] = __float2bfloat16(v);
                }
            }
        }
    }
}

// =============================================================
// xg GEMM, m97 structure: C[4096,4096] = A[4096,1024] @ W[4096,1024]^T
// 128x128 block tile, BK=32, double-buffered LDS via global_load_lds(16B),
// 4 waves (2x2), each wave 64x64 = 4x4 frags of 16x16x32.
// Epilogue: + g_featb[b] (f32), store bf16 to g_xg.
// Expected: ~45us/dispatch, MfmaUtil ~35% (vs 189us / 7.3% direct-global).
// =============================================================
__global__ __launch_bounds__(256) void gemm_xg(size_t seq_off, size_t w_off)
{
    __shared__ unsigned short lA[2][128 * 32];   // 8 KB per buffer
    __shared__ unsigned short lB[2][128 * 32];   // total 32 KB -> ~3 blocks/CU

    const int tid  = threadIdx.x;
    const int lane = tid & 63, wv = tid >> 6;
    const int row  = lane & 15, quad = lane >> 4;
    const int wr = wv >> 1, wc = wv & 1;
    const int m_base = blockIdx.y * 128;
    const int n_base = blockIdx.x * 128;

    const __hip_bfloat16* A  = BPc(g_seq) + seq_off + (size_t)m_base * 1024;
    const __hip_bfloat16* Wt = BPc(g_Wih) + w_off   + (size_t)n_base * 1024;

    f32x4 acc[4][4] = {};

    // stage K-tile kt into buffer bf: slots s = it*256+tid; LDS granule == s
    // (linear dest required by global_load_lds; wave-uniform base + lane*16)
    auto STAGE = [&](int bf, int kt) {
        const int k0 = kt * 32;
#pragma unroll
        for (int it = 0; it < 2; ++it) {
            const int r  = (tid >> 2) + it * 64;     // row 0..127
            const int kc = k0 + (tid & 3) * 8;       // k granule within tile
            unsigned short* dA = &lA[bf][(size_t)(it * 256 + wv * 64) * 8];
            unsigned short* dB = &lB[bf][(size_t)(it * 256 + wv * 64) * 8];
            gload16(A  + (size_t)r * 1024 + kc, dA);
            gload16(Wt + (size_t)r * 1024 + kc, dB);
        }
    };

    STAGE(0, 0);
    asm volatile("s_waitcnt vmcnt(0)" ::: "memory");
    __syncthreads();

    for (int kt = 0; kt < 32; ++kt) {
        const int cur = kt & 1;
        if (kt + 1 < 32) STAGE(cur ^ 1, kt + 1);     // prefetch next tile (T3: issue before ds_read)

        const unsigned short* pa = &lA[cur][(size_t)(wr * 64 + row) * 32 + quad * 8];
        const unsigned short* pb = &lB[cur][(size_t)(wc * 64 + row) * 32 + quad * 8];
        bf16x8 a[4], b[4];
#pragma unroll
        for (int i = 0; i < 4; ++i) a[i] = ld8(BPc(pa + (size_t)i * 16 * 32));
#pragma unroll
        for (int j = 0; j < 4; ++j) b[j] = ld8(BPc(pb + (size_t)j * 16 * 32));
#pragma unroll
        for (int i = 0; i < 4; ++i)
#pragma unroll
            for (int j = 0; j < 4; ++j)
                acc[i][j] = __builtin_amdgcn_mfma_f32_16x16x32_bf16(a[i], b[j], acc[i][j], 0, 0, 0);

        asm volatile("s_waitcnt vmcnt(0)" ::: "memory");
        __syncthreads();
    }

#pragma unroll
    for (int i = 0; i < 4; ++i) {
#pragma unroll
        for (int j = 0; j < 4; ++j) {
            const int n = n_base + wc * 64 + 16 * j + row;
#pragma unroll
            for (int r = 0; r < 4; ++r) {
                const int m = m_base + wr * 64 + 16 * i + quad * 4 + r;
                float v = acc[i][j][r] + g_featb[(size_t)(m & 255) * G4 + n];
                BP(g_xg)[(size_t)m * G4 + n] = __float2bfloat16(v);
            }
        }
    }
}

// =============================================================
// One LSTM timestep: gates = g_xg[tt] + h(t-1) @ Whh^T; cell update; mask.
// Grid (H/16=64, B/64=4) = 256 blocks; block 512 thr = 8 waves = 2 waves/SIMD.
// Wave wv: cp = wv&1 selects gates {2cp, 2cp+1}; kq = wv>>1 selects K quarter
// [kq*256, kq*256+256). Each wave: 64(b) x 32(gate-col) partial, 8 K-steps.
//   -> A(h) redundancy 4x -> 2x, dependent chain /4, 2 waves/SIMD for hiding.
// Partials land in gsum[kq] (stride-17 padded f32 LDS), one barrier, then
// element-wise update sums the 4 quarters. xg is folded in by wave kq==i for
// row-quarter i (each location exactly once).
// =============================================================
__global__ __launch_bounds__(512) void lstm_step(
    const int* __restrict__ length,
    float* __restrict__ out_t,          // layer-1 only (else nullptr)
    int t, int tt, int layer)
{
    __shared__ float gsum[4][4 * 64 * 17];   // [kq][(gate*64+lb)*17+row]  ~69.6 KB

    const int tid  = threadIdx.x;
    const int lane = tid & 63, wv = tid >> 6;
    const int cp = wv & 1, kq = wv >> 1;
    const int row = lane & 15, quad = lane >> 4;
    const int j0 = blockIdx.x * 16;
    const int b0 = blockIdx.y * 64;

    const __hip_bfloat16* Whh  = BPc(g_Whh) + (size_t)layer * G4 * 1024;
    const __hip_bfloat16* h_in = (t > 0) ? BPc(g_h[(t + 1) & 1]) : nullptr;
    __hip_bfloat16* h_out = BP(g_h[t & 1]);

    f32x4 acc[4][2] = {};
    if (h_in) {
        const __hip_bfloat16* ap = h_in + (size_t)(b0 + row) * HH + kq * 256 + quad * 8;
        const __hip_bfloat16* w0 = Whh +
            (size_t)((2 * cp + 0) * HH + j0 + row) * HH + kq * 256 + quad * 8;
        const __hip_bfloat16* w1 = w0 + (size_t)HH * HH;   // gate 2cp+1 rows
#pragma unroll 4
        for (int k0 = 0; k0 < 256; k0 += 32) {
            bf16x8 bf0 = ld8(w0 + k0);
            bf16x8 bf1 = ld8(w1 + k0);
#pragma unroll
            for (int i = 0; i < 4; ++i) {
                bf16x8 af = ld8(ap + (size_t)(16 * i) * HH + k0);
                acc[i][0] = __builtin_amdgcn_mfma_f32_16x16x32_bf16(af, bf0, acc[i][0], 0, 0, 0);
                acc[i][1] = __builtin_amdgcn_mfma_f32_16x16x32_bf16(af, bf1, acc[i][1], 0, 0, 0);
            }
        }
    }

    const __hip_bfloat16* xg = BPc(g_xg) + (size_t)tt * BB * G4;
#pragma unroll
    for (int i = 0; i < 4; ++i) {
        const bool addxg = (i == kq);        // fold xg in exactly once per location
#pragma unroll
        for (int jj = 0; jj < 2; ++jj) {
            const int g = 2 * cp + jj;
#pragma unroll
            for (int r = 0; r < 4; ++r) {
                const int lb = 16 * i + quad * 4 + r;       // 0..63
                float v = acc[i][jj][r];
                if (addxg)
                    v += (float)xg[(size_t)(b0 + lb) * G4 + g * HH + j0 + row];
                gsum[kq][(g * 64 + lb) * 17 + row] = v;
            }
        }
    }
    __syncthreads();

    for (int e = tid; e < 64 * 16; e += 512) {
        const int lb = e >> 4, lj = e & 15;
        const int b = b0 + lb, jc = j0 + lj;
        const int xi = (0 * 64 + lb) * 17 + lj;
        const int xf = (1 * 64 + lb) * 17 + lj;
        const int xg2 = (2 * 64 + lb) * 17 + lj;
        const int xo = (3 * 64 + lb) * 17 + lj;
        const float gi = gsum[0][xi] + gsum[1][xi] + gsum[2][xi] + gsum[3][xi];
        const float gf = gsum[0][xf] + gsum[1][xf] + gsum[2][xf] + gsum[3][xf];
        const float gg = gsum[0][xg2] + gsum[1][xg2] + gsum[2][xg2] + gsum[3][xg2];
        const float go = gsum[0][xo] + gsum[1][xo] + gsum[2][xo] + gsum[3][xo];

        const size_t idx = (size_t)b * HH + jc;
        float hv;
        if (t < length[b]) {
            const float c_old = g_c[idx];
            const float si = 1.0f / (1.0f + __expf(-gi));
            const float sf = 1.0f / (1.0f + __expf(-gf));
            const float so = 1.0f / (1.0f + __expf(-go));
            const float tg = tanhf(gg);
            const float c_new = sf * c_old + si * tg;
            g_c[idx] = c_new;
            hv = so * tanhf(c_new);
        } else {
            hv = h_in ? (float)h_in[idx] : 0.0f;   // frozen past sequence end
        }
        const __hip_bfloat16 hb = __float2bfloat16(hv);
        h_out[idx] = hb;
        if (layer == 0) BP(g_seq)[(size_t)t * BB * HH + idx] = hb;
        else            out_t[idx] = hv;
    }
}

// ---------------- small utility kernels ----------------
__global__ __launch_bounds__(256) void zero_c() {
    g_c[blockIdx.x * 256 + threadIdx.x] = 0.0f;
}
__global__ __launch_bounds__(256) void finish_layer(float* __restrict__ hn,
                                                    float* __restrict__ cn)
{
    const int i = blockIdx.x * 256 + threadIdx.x;
    hn[i] = (float)BPc(g_h[(TT - 1) & 1])[i];
    cn[i] = g_c[i];
}

// =============================================================
// host launcher — kernel launches ONLY (graph-capture safe)
// =============================================================
extern "C" void kernel_launch(void* const* d_in, const int* in_sizes, int n_in,
                              void* d_out, int out_size, void* d_ws, size_t ws_size,
                              hipStream_t stream)
{
    const float* x        = (const float*)d_in[0];  // (T,B,D)   f32
    const float* features = (const float*)d_in[1];  // (B,F)     f32
    const float* Wih      = (const float*)d_in[2];  // (L,4H,D)  f32
    const float* Whh      = (const float*)d_in[3];  // (L,4H,H)  f32
    const float* Wfh      = (const float*)d_in[4];  // (L,4H,F)  f32
    const float* bvec     = (const float*)d_in[5];  // (L,4H)    f32
    const int*   length   = (const int*)d_in[6];    // (B,)      int
    float* out = (float*)d_out;                     // f32 outputs

    const size_t nX = (size_t)TT * BB * DD;
    const size_t nW = (size_t)2 * G4 * 1024;
    const size_t nF = (size_t)BB * 1024;
    cvt_bf16<<<(int)(nX / 1024), 256, 0, stream>>>(0, x, nX);
    cvt_bf16<<<(int)(nW / 1024), 256, 0, stream>>>(1, Wih, nW);
    cvt_bf16<<<(int)(nW / 1024), 256, 0, stream>>>(2, Whh, nW);
    cvt_bf16<<<(int)(nW / 1024), 256, 0, stream>>>(3, Wfh, nW);
    cvt_bf16<<<(int)(nF / 1024), 256, 0, stream>>>(4, features, nF);

    float* out_hn = out + (size_t)TT * BB * HH;
    float* out_cn = out_hn + (size_t)2 * BB * HH;

    for (int l = 0; l < 2; ++l) {
        const size_t w_off = (size_t)l * G4 * 1024;

        // g_featb = feat @ Wfh[l]^T + b[l]   (f32 [B,4H])
        gemm_k<true><<<dim3(G4 / 64, BB / 128), 256, 0, stream>>>(
            0, w_off, bvec + (size_t)l * G4);
        zero_c<<<BB * HH / 256, 256, 0, stream>>>();

        for (int c0 = 0; c0 < TT; c0 += CHT) {
            // g_xg = g_seq[c0:c0+CHT] @ Wih[l]^T + g_featb  (bf16 [CHT*B,4H])
            gemm_xg<<<dim3(G4 / 128, CHT * BB / 128), 256, 0, stream>>>(
                (size_t)c0 * BB * DD, w_off);

            for (int tt2 = 0; tt2 < CHT; ++tt2) {
                const int t = c0 + tt2;
                lstm_step<<<dim3(HH / 16, BB / 64), 512, 0, stream>>>(
                    length, out + (size_t)t * BB * HH, t, tt2, l);
            }
        }

        finish_layer<<<BB * HH / 256, 256, 0, stream>>>(
            out_hn + (size_t)l * BB * HH, out_cn + (size_t)l * BB * HH);
    }
}